// Round 15
// baseline (3470.867 us; speedup 1.0000x reference)
//
#include <hip/hip_runtime.h>
#include <hip/hip_fp16.h>

#define N 4096
#define IN_DIM 128
#define T_STEPS 2048
#define KSLOTS 576           // uniform padded ELL row width; max nnz ~490 (mean 409.6, sd 19.2)
#define CHUNKS (KSLOTS / 64) // 9, uniform for all rows (R21 packing REGRESSED: +11% conflicts)
#define NBLOCKS 256
#define NTHREADS 512
#define ROWS_PER_WAVE 2
#define ROWS_PER_BLOCK (ROWS_PER_WAVE * (NTHREADS / 64))   // 16
#define SENTINEL_BITS 0x7FC00001u   // f32 qNaN; h finite -> producers never write this
#define H16_SENT 0x7E01u            // fp16 qNaN; RNE conversion of finite h never yields it
#define H16_BYTES_PER_STEP (N * 2)  // 8192

typedef float f32x4 __attribute__((ext_vector_type(4)));

// ---------------------------------------------------------------------------
// h_lds layout permutation (R24). Column c lives at float index pi(c):
//   g = c>>3 (fp16 granule), w = g>>6, l = g&63, b = (c>>2)&1, r = c&3
//   P = 128w + 64b + l   (16B granule position);  pi(c) = 4P + r
// Consumer thread tid=(w,l) then writes its two converted f32x4s at granules
// (w<<7)+l and (w<<7)+64+l: each staging instruction spreads lane%8 across
// ALL 8 bank groups = the 8-way hardware floor (R23's [2t],[2t+1] pattern hit
// only even groups -> 16-way, +62% conflicts, canceling the fp16 poll gain).
// The gather is layout-agnostic: build_ell stores pi(c) directly as the col.
// ---------------------------------------------------------------------------
__device__ __forceinline__ int perm_col(int c) {
    int g = c >> 3, w = g >> 6, l = g & 63, b = (c >> 2) & 1, r = c & 3;
    int P = (w << 7) + (b << 6) + l;
    return (P << 2) + r;
}

// ---------------------------------------------------------------------------
// Kernel 0: poison out (f32 qNaN) and the fp16 relay staging (0x7E01 pairs),
// write-through agent scope -> at the coherence point before any poll.
// Replay tripwire: any sync bug propagates NaN -> loud absmax failure.
// ---------------------------------------------------------------------------
__global__ void init_sentinel(float* __restrict__ out, unsigned int* __restrict__ h16) {
    const size_t i = (size_t)blockIdx.x * blockDim.x + threadIdx.x;
    __hip_atomic_store(&out[i], __uint_as_float(SENTINEL_BITS),
                       __ATOMIC_RELAXED, __HIP_MEMORY_SCOPE_AGENT);
    if (h16 && i < ((size_t)T_STEPS * H16_BYTES_PER_STEP / 4))
        __hip_atomic_store(&h16[i], (H16_SENT << 16) | H16_SENT,
                           __ATOMIC_RELAXED, __HIP_MEMORY_SCOPE_AGENT);
}

// ---------------------------------------------------------------------------
// Kernel 1: dense W -> uniform padded ELL, bank-aware chunk assignment on the
// PERMUTED layout's bank key (c>>3)&31 (pi changes the LDS bank of column c
// from c%32 to (c>>3)%32). Stored col = pi(c) (step kernel uses it as the
// raw float index). Padding val=0, col=0: pi(0)=0, broadcast stays free.
// Zero-padding slots load-balance banks (R21 lesson) — spread kept at 9.
// ---------------------------------------------------------------------------
__global__ void build_ell(const float* __restrict__ W,
                          float* __restrict__ vals,
                          unsigned short* __restrict__ cols) {
    __shared__ float sval[KSLOTS];
    __shared__ unsigned short scol[KSLOTS];
    __shared__ float slot_val[KSLOTS];
    __shared__ unsigned short slot_col[KSLOTS];
    __shared__ int chunk_fill[CHUNKS];
    __shared__ int cnt;

    const int r = blockIdx.x;
    const int tid = threadIdx.x;
    if (tid == 0) cnt = 0;
    if (tid < CHUNKS) chunk_fill[tid] = 0;
    __syncthreads();

    const float* wrow = W + (size_t)r * N;
    for (int j = tid; j < N; j += blockDim.x) {
        float w = wrow[j];
        if (w != 0.0f) {
            int p = atomicAdd(&cnt, 1);
            if (p < KSLOTS) { sval[p] = w; scol[p] = (unsigned short)j; }
        }
    }
    __syncthreads();
    for (int j = tid; j < KSLOTS; j += blockDim.x) { slot_val[j] = 0.0f; slot_col[j] = 0; }
    __syncthreads();

    if (tid < 32) {  // one thread per (permuted-layout) bank
        int k = 0;
        const int n = (cnt < KSLOTS) ? cnt : KSLOTS;
        for (int p = 0; p < n; ++p) {
            int c = scol[p];
            if (((c >> 3) & 31) == tid) {          // bank key under pi
                int ch0 = (k + tid) % CHUNKS;
                for (int probe = 0; probe < CHUNKS; ++probe) {
                    int cc = ch0 + probe; if (cc >= CHUNKS) cc -= CHUNKS;
                    int pos = atomicAdd(&chunk_fill[cc], 1);
                    if (pos < 64) {
                        slot_val[cc * 64 + pos] = sval[p];
                        slot_col[cc * 64 + pos] = (unsigned short)perm_col(c);
                        break;
                    }
                }
                ++k;
            }
        }
    }
    __syncthreads();

    float* vrow = vals + (size_t)r * KSLOTS;
    unsigned short* crow = cols + (size_t)r * KSLOTS;
    for (int j = tid; j < KSLOTS; j += blockDim.x) { vrow[j] = slot_val[j]; crow[j] = slot_col[j]; }
}

// ---------------------------------------------------------------------------
// Coherent accesses at the coherence point (bypass L1+L2). Proven forms.
// ---------------------------------------------------------------------------
__device__ __forceinline__ f32x4 load_coherent_x4(const float* p) {
    f32x4 v;
    asm volatile("global_load_dwordx4 %0, %1, off sc0 sc1\n\t"
                 "s_waitcnt vmcnt(0)"
                 : "=v"(v) : "v"(p) : "memory");
    return v;
}

__device__ __forceinline__ void load_coherent_x4_pair(const float* p0, const float* p1,
                                                      f32x4* v0, f32x4* v1) {
    f32x4 a, b;
    asm volatile("global_load_dwordx4 %0, %2, off sc0 sc1\n\t"
                 "global_load_dwordx4 %1, %3, off sc0 sc1\n\t"
                 "s_waitcnt vmcnt(0)"
                 : "=v"(a), "=v"(b) : "v"(p0), "v"(p1) : "memory");
    *v0 = a; *v1 = b;
}

__device__ __forceinline__ void store_coherent_x4(float* p, f32x4 v) {
    asm volatile("global_store_dwordx4 %0, %1, off sc0 sc1"
                 :: "v"(p), "v"(v) : "memory");
}

__device__ __forceinline__ bool granule_not_ready(f32x4 hv) {
    return (__float_as_uint(hv.x) == SENTINEL_BITS) |
           (__float_as_uint(hv.y) == SENTINEL_BITS) |
           (__float_as_uint(hv.z) == SENTINEL_BITS) |
           (__float_as_uint(hv.w) == SENTINEL_BITS);
}

// 16B granule of 8 fp16 values: not ready iff ANY u16 == H16_SENT.
__device__ __forceinline__ bool h16_not_ready(f32x4 hv) {
    unsigned int w0 = __float_as_uint(hv.x), w1 = __float_as_uint(hv.y);
    unsigned int w2 = __float_as_uint(hv.z), w3 = __float_as_uint(hv.w);
    return ((w0 & 0xFFFFu) == H16_SENT) | ((w0 >> 16) == H16_SENT) |
           ((w1 & 0xFFFFu) == H16_SENT) | ((w1 >> 16) == H16_SENT) |
           ((w2 & 0xFFFFu) == H16_SENT) | ((w2 >> 16) == H16_SENT) |
           ((w3 & 0xFFFFu) == H16_SENT) | ((w3 >> 16) == H16_SENT);
}

// Branch-free tanh (validated R6-first-launch + R9: absmax 3.9e-3 unchanged).
__device__ __forceinline__ float fast_tanh(float v) {
    float ax = __builtin_fabsf(v);
    float e  = __builtin_amdgcn_exp2f(ax * 2.88539008177793f);  // 2*log2(e)
    float r  = 1.0f - 2.0f * __builtin_amdgcn_rcpf(e + 1.0f);
    return __builtin_copysignf(r, v);
}

// ---------------------------------------------------------------------------
// R19: 64-lane sum via the canonical GCN DPP ladder (pure VALU, off the LDS
// pipe). Lane 63 holds the total.
// ---------------------------------------------------------------------------
__device__ __forceinline__ float dpp_reduce_add(float v) {
    int t;
    t = __builtin_amdgcn_update_dpp(0, __float_as_int(v), 0x111, 0xf, 0xf, true); // shr:1
    v += __int_as_float(t);
    t = __builtin_amdgcn_update_dpp(0, __float_as_int(v), 0x112, 0xf, 0xf, true); // shr:2
    v += __int_as_float(t);
    t = __builtin_amdgcn_update_dpp(0, __float_as_int(v), 0x114, 0xf, 0xf, true); // shr:4
    v += __int_as_float(t);
    t = __builtin_amdgcn_update_dpp(0, __float_as_int(v), 0x118, 0xf, 0xf, true); // shr:8
    v += __int_as_float(t);
    t = __builtin_amdgcn_update_dpp(0, __float_as_int(v), 0x142, 0xa, 0xf, true); // bcast15
    v += __int_as_float(t);
    t = __builtin_amdgcn_update_dpp(0, __float_as_int(v), 0x143, 0xc, 0xf, true); // bcast31
    v += __int_as_float(t);
    return v;   // lane 63 = sum over all 64 lanes
}

// ---------------------------------------------------------------------------
// Kernel 2: persistent step kernel. R24 = R23 (fp16 relay poll: 2MB/round,
// detect==load, per-step-indexed staging; plain cached f32 out stores) +
// the pi staging layout so the two h_lds f32x4 writes per thread sit at the
// 8-way bank floor instead of R23's 16-way. Everything else byte-identical.
// ---------------------------------------------------------------------------
__global__ void __launch_bounds__(NTHREADS, 1) esn_steps(
    const float* __restrict__ x,
    const float* __restrict__ W_in,
    const float* __restrict__ vals,
    const unsigned short* __restrict__ cols,
    float* __restrict__ out,
    char* __restrict__ h16,
    int use_h16) {

    __shared__ float h_lds[N];       // full previous state, 16 KB (pi layout)
    __shared__ __align__(16) float hout[ROWS_PER_BLOCK];  // block's 16 new rows

    const int tid  = threadIdx.x;
    const int lane = tid & 63;
    const int wave = tid >> 6;
    const int blockBase = blockIdx.x * ROWS_PER_BLOCK;
    const int base = blockBase + wave * ROWS_PER_WAVE;  // 2 rows/wave

    // Per-row W_in slices.
    float w0[ROWS_PER_WAVE], w1[ROWS_PER_WAVE];
    #pragma unroll
    for (int j = 0; j < ROWS_PER_WAVE; ++j) {
        w0[j] = W_in[(base + j) * IN_DIM + lane];
        w1[j] = W_in[(base + j) * IN_DIM + 64 + lane];
    }

    // Hoist the 2-row ELL slice into registers (18 vals + 18 byte offsets).
    // cols already hold pi(c): rc = pi(c)*4 = byte offset in the pi layout.
    float rv[ROWS_PER_WAVE][CHUNKS];
    int   rc[ROWS_PER_WAVE][CHUNKS];
    #pragma unroll
    for (int j = 0; j < ROWS_PER_WAVE; ++j) {
        const float* vp = vals + (size_t)(base + j) * KSLOTS;
        const unsigned short* cp = cols + (size_t)(base + j) * KSLOTS;
        #pragma unroll
        for (int i = 0; i < CHUNKS; ++i) {
            rv[j][i] = vp[(i << 6) + lane];
            rc[j][i] = ((int)cp[(i << 6) + lane]) << 2;
        }
    }

    const int i4 = tid << 2;
    const int gLo = (wave << 7) + lane;        // pi granule of h[8tid..8tid+4)
    const int gHi = gLo + 64;                  // pi granule of h[8tid+4..8tid+8)

    for (int t = 0; t < T_STEPS; ++t) {
        // ---- x_t via cached global loads (L1 broadcast) ----
        const float xa = x[t * IN_DIM + lane];
        const float xb = x[t * IN_DIM + 64 + lane];

        // ---- stage h_{t-1} ----
        if (t > 0) {
            if (use_h16) {
                // One 16B fp16 granule = 8 h values; proven paced ladder.
                const float* addr = (const float*)(h16 +
                    (size_t)(t - 1) * H16_BYTES_PER_STEP + (tid << 4));
                f32x4 hv;
                __builtin_amdgcn_s_sleep(8);
                hv = load_coherent_x4(addr);
                if (h16_not_ready(hv)) {
                    __builtin_amdgcn_s_sleep(1);
                    hv = load_coherent_x4(addr);
                    if (h16_not_ready(hv)) {
                        __builtin_amdgcn_s_sleep(2);
                        hv = load_coherent_x4(addr);
                        while (h16_not_ready(hv)) {
                            __builtin_amdgcn_s_sleep(4);
                            hv = load_coherent_x4(addr);
                        }
                    }
                }
                unsigned int u0 = __float_as_uint(hv.x), u1 = __float_as_uint(hv.y);
                unsigned int u2 = __float_as_uint(hv.z), u3 = __float_as_uint(hv.w);
                f32x4 lo, hi;
                lo.x = __half2float(__ushort_as_half((unsigned short)(u0 & 0xFFFFu)));
                lo.y = __half2float(__ushort_as_half((unsigned short)(u0 >> 16)));
                lo.z = __half2float(__ushort_as_half((unsigned short)(u1 & 0xFFFFu)));
                lo.w = __half2float(__ushort_as_half((unsigned short)(u1 >> 16)));
                hi.x = __half2float(__ushort_as_half((unsigned short)(u2 & 0xFFFFu)));
                hi.y = __half2float(__ushort_as_half((unsigned short)(u2 >> 16)));
                hi.z = __half2float(__ushort_as_half((unsigned short)(u3 & 0xFFFFu)));
                hi.w = __half2float(__ushort_as_half((unsigned short)(u3 >> 16)));
                ((f32x4*)h_lds)[gLo] = lo;     // banks: lane%8 -> all 8 groups
                ((f32x4*)h_lds)[gHi] = hi;     // 8-way floor (was 16-way)
            } else {
                // Fallback: R22 paired f32 poll on out[t-1], pi-placed.
                f32x4 hv0, hv1;
                const float* a0 = out + (size_t)(t - 1) * N + i4;
                const float* a1 = a0 + (NTHREADS * 4);
                __builtin_amdgcn_s_sleep(8);
                load_coherent_x4_pair(a0, a1, &hv0, &hv1);
                if (granule_not_ready(hv0) | granule_not_ready(hv1)) {
                    __builtin_amdgcn_s_sleep(1);
                    load_coherent_x4_pair(a0, a1, &hv0, &hv1);
                    if (granule_not_ready(hv0) | granule_not_ready(hv1)) {
                        __builtin_amdgcn_s_sleep(2);
                        load_coherent_x4_pair(a0, a1, &hv0, &hv1);
                        while (granule_not_ready(hv0) | granule_not_ready(hv1)) {
                            __builtin_amdgcn_s_sleep(4);
                            load_coherent_x4_pair(a0, a1, &hv0, &hv1);
                        }
                    }
                }
                // f32 granule G: pos = 128*(G>>7) + 64*(G&1) + ((G>>1)&63)
                const int G0 = tid, G1 = tid + NTHREADS;
                const int p0 = ((G0 >> 7) << 7) + ((G0 & 1) << 6) + ((G0 >> 1) & 63);
                const int p1 = ((G1 >> 7) << 7) + ((G1 & 1) << 6) + ((G1 >> 1) & 63);
                ((f32x4*)h_lds)[p0] = hv0;
                ((f32x4*)h_lds)[p1] = hv1;
            }
        } else {
            ((f32x4*)h_lds)[gLo] = (f32x4)(0.0f);
            ((f32x4*)h_lds)[gHi] = (f32x4)(0.0f);
        }
        __syncthreads();   // barrier 1: h_lds fully staged

        // ---- 2 row dots: input part + register-ELL sparse gather ----
        float acc[ROWS_PER_WAVE];
        #pragma unroll
        for (int j = 0; j < ROWS_PER_WAVE; ++j) acc[j] = w0[j] * xa + w1[j] * xb;

        #pragma unroll
        for (int j = 0; j < ROWS_PER_WAVE; ++j) {
            #pragma unroll
            for (int i = 0; i < CHUNKS; ++i) {
                acc[j] += rv[j][i] * *(const float*)((const char*)h_lds + rc[j][i]);
            }
        }

        // ---- DPP reduce (VALU pipe): lane 63 holds both sums ----
        acc[0] = dpp_reduce_add(acc[0]);
        acc[1] = dpp_reduce_add(acc[1]);

        if (lane == 63) {
            float hp0 = h_lds[perm_col(base + 0)];
            float hp1 = h_lds[perm_col(base + 1)];
            hout[wave * ROWS_PER_WAVE + 0] = 0.7f * hp0 + 0.3f * fast_tanh(acc[0]);
            hout[wave * ROWS_PER_WAVE + 1] = 0.7f * hp1 + 0.3f * fast_tanh(acc[1]);
        }
        __syncthreads();   // barrier 2: collect done + all h_lds reads done

        // ---- PUBLISH ----
        if (use_h16) {
            // fp16 relay line FIRST (the polled object): lanes 0-1, one 16B
            // coherent store each = the block's 32B line, single moment.
            if (tid < 2) {
                const float* hp = &hout[tid * 8];
                __half2 p0 = __floats2half2_rn(hp[0], hp[1]);
                __half2 p1 = __floats2half2_rn(hp[2], hp[3]);
                __half2 p2 = __floats2half2_rn(hp[4], hp[5]);
                __half2 p3 = __floats2half2_rn(hp[6], hp[7]);
                f32x4 pk;
                pk.x = __uint_as_float(*(unsigned int*)&p0);
                pk.y = __uint_as_float(*(unsigned int*)&p1);
                pk.z = __uint_as_float(*(unsigned int*)&p2);
                pk.w = __uint_as_float(*(unsigned int*)&p3);
                store_coherent_x4((float*)(h16 + (size_t)t * H16_BYTES_PER_STEP
                                           + blockIdx.x * 32 + (tid << 4)), pk);
            }
            // f32 out line: PLAIN cached stores (never polled; host sees it
            // via kernel-end writeback). hout is natural row order.
            if (tid < ROWS_PER_BLOCK / 4) {
                f32x4 hv4 = ((const f32x4*)hout)[tid];
                *(((f32x4*)(out + (size_t)t * N + blockBase)) + tid) = hv4;
            }
        } else {
            if (tid < ROWS_PER_BLOCK / 4) {
                f32x4 hv4 = ((const f32x4*)hout)[tid];
                store_coherent_x4(out + (size_t)t * N + blockBase + (tid << 2), hv4);
            }
        }
    }
}

// ---------------------------------------------------------------------------
// Workspace layout (bytes):
//   [0, +N*KSLOTS*4)       ELL vals (f32)            9.44 MB
//   [.., +N*KSLOTS*2)      ELL cols (u16)            4.72 MB
//   [.., +T_STEPS*N*2)     fp16 relay staging        16 MB  (guarded)
// Guard: if ws_size is short, use_h16=0 -> R22 behavior (pi-placed).
// ---------------------------------------------------------------------------
extern "C" void kernel_launch(void* const* d_in, const int* in_sizes, int n_in,
                              void* d_out, int out_size, void* d_ws, size_t ws_size,
                              hipStream_t stream) {
    const float* x    = (const float*)d_in[0];  // [2048,128]
    const float* W_in = (const float*)d_in[1];  // [4096,128]
    const float* W    = (const float*)d_in[2];  // [4096,4096]
    float* out = (float*)d_out;                 // [2048,4096]

    char* ws = (char*)d_ws;
    float* vals = (float*)ws;
    unsigned short* cols = (unsigned short*)(ws + (size_t)N * KSLOTS * 4);

    const size_t ell_bytes = (size_t)N * KSLOTS * 6;            // 14,155,776
    const size_t h16_bytes = (size_t)T_STEPS * H16_BYTES_PER_STEP;  // 16 MB
    int use_h16 = (ws_size >= ell_bytes + h16_bytes) ? 1 : 0;
    char* h16 = use_h16 ? (ws + ell_bytes) : nullptr;

    init_sentinel<<<(T_STEPS * N) / 1024, 1024, 0, stream>>>(
        out, (unsigned int*)h16);
    build_ell<<<N, 256, 0, stream>>>(W, vals, cols);

    void* args[] = {(void*)&x, (void*)&W_in, (void*)&vals, (void*)&cols,
                    (void*)&out, (void*)&h16, (void*)&use_h16};
    hipLaunchCooperativeKernel((void*)esn_steps, dim3(NBLOCKS), dim3(NTHREADS),
                               args, 0, stream);
}

// Round 16
// 3228.483 us; speedup vs baseline: 1.0751x; 1.0751x over previous
//
#include <hip/hip_runtime.h>
#include <hip/hip_fp16.h>

#define N 4096
#define IN_DIM 128
#define T_STEPS 2048
#define KSLOTS 576           // uniform padded ELL row width; max nnz ~490 (mean 409.6, sd 19.2)
#define CHUNKS (KSLOTS / 64) // 9, uniform for all rows (R21 packing REGRESSED: +11% conflicts)
#define NBLOCKS 256
#define NTHREADS 512
#define ROWS_PER_WAVE 2
#define ROWS_PER_BLOCK (ROWS_PER_WAVE * (NTHREADS / 64))   // 16
#define SENTINEL_BITS 0x7FC00001u   // f32 qNaN; h finite -> producers never write this
#define H16_SENT 0x7E01u            // fp16 qNaN; RNE conversion of finite h never yields it
#define H16_BYTES_PER_STEP (N * 2)  // 8192

typedef float f32x4 __attribute__((ext_vector_type(4)));

// ---------------------------------------------------------------------------
// h_lds layout permutation (R24/R25). Column c lives at float index pi(c):
//   g = c>>3, w = g>>6, l = g&63, b = (c>>2)&1, r = c&3
//   P = 128w + 64b + l;  pi(c) = 4P + r
// TRUE BANK of pi(c): byte=16P+4r -> bank=(4P+r)%32; 512w,256b == 0 mod 32
//   => bank(pi(c)) = 4*((c>>3)&7) + (c&3)          [R25's corrected key]
// R24 BUG: build_ell balanced on (c>>3)&31, which aliases 4 c-groups per
// bank (bit 2 of c and bits 6-7 of c>>3 are bank-irrelevant) -> gather
// imbalance, conflicts +40%. R25 balances on the true bank.
// Staging writes (granules (w<<7)+l, (w<<7)+64+l) hit the 8-way floor:
// instruction bank group = lane%8 covers all 8 groups (verified R24 math).
// ---------------------------------------------------------------------------
__device__ __forceinline__ int perm_col(int c) {
    int g = c >> 3, w = g >> 6, l = g & 63, b = (c >> 2) & 1, r = c & 3;
    int P = (w << 7) + (b << 6) + l;
    return (P << 2) + r;
}

__device__ __forceinline__ int perm_bank(int c) {     // true LDS bank of pi(c)
    return (((c >> 3) & 7) << 2) + (c & 3);
}

// ---------------------------------------------------------------------------
// Kernel 0: poison out (f32 qNaN) and the fp16 relay staging (0x7E01 pairs),
// write-through agent scope -> at the coherence point before any poll.
// Replay tripwire: any sync bug propagates NaN -> loud absmax failure.
// ---------------------------------------------------------------------------
__global__ void init_sentinel(float* __restrict__ out, unsigned int* __restrict__ h16) {
    const size_t i = (size_t)blockIdx.x * blockDim.x + threadIdx.x;
    __hip_atomic_store(&out[i], __uint_as_float(SENTINEL_BITS),
                       __ATOMIC_RELAXED, __HIP_MEMORY_SCOPE_AGENT);
    if (h16 && i < ((size_t)T_STEPS * H16_BYTES_PER_STEP / 4))
        __hip_atomic_store(&h16[i], (H16_SENT << 16) | H16_SENT,
                           __ATOMIC_RELAXED, __HIP_MEMORY_SCOPE_AGENT);
}

// ---------------------------------------------------------------------------
// Kernel 1: dense W -> uniform padded ELL, chunk assignment balanced on the
// TRUE bank of the permuted layout (perm_bank). Stored col = pi(c) (raw
// float index for the step kernel). Padding val=0, col=0 (pi(0)=0, free
// broadcast). Zero-padding slots load-balance banks (R21) — spread kept 9.
// ---------------------------------------------------------------------------
__global__ void build_ell(const float* __restrict__ W,
                          float* __restrict__ vals,
                          unsigned short* __restrict__ cols) {
    __shared__ float sval[KSLOTS];
    __shared__ unsigned short scol[KSLOTS];
    __shared__ float slot_val[KSLOTS];
    __shared__ unsigned short slot_col[KSLOTS];
    __shared__ int chunk_fill[CHUNKS];
    __shared__ int cnt;

    const int r = blockIdx.x;
    const int tid = threadIdx.x;
    if (tid == 0) cnt = 0;
    if (tid < CHUNKS) chunk_fill[tid] = 0;
    __syncthreads();

    const float* wrow = W + (size_t)r * N;
    for (int j = tid; j < N; j += blockDim.x) {
        float w = wrow[j];
        if (w != 0.0f) {
            int p = atomicAdd(&cnt, 1);
            if (p < KSLOTS) { sval[p] = w; scol[p] = (unsigned short)j; }
        }
    }
    __syncthreads();
    for (int j = tid; j < KSLOTS; j += blockDim.x) { slot_val[j] = 0.0f; slot_col[j] = 0; }
    __syncthreads();

    if (tid < 32) {  // one thread per TRUE bank of the permuted layout
        int k = 0;
        const int n = (cnt < KSLOTS) ? cnt : KSLOTS;
        for (int p = 0; p < n; ++p) {
            int c = scol[p];
            if (perm_bank(c) == tid) {             // R25: exact bank key
                int ch0 = (k + tid) % CHUNKS;
                for (int probe = 0; probe < CHUNKS; ++probe) {
                    int cc = ch0 + probe; if (cc >= CHUNKS) cc -= CHUNKS;
                    int pos = atomicAdd(&chunk_fill[cc], 1);
                    if (pos < 64) {
                        slot_val[cc * 64 + pos] = sval[p];
                        slot_col[cc * 64 + pos] = (unsigned short)perm_col(c);
                        break;
                    }
                }
                ++k;
            }
        }
    }
    __syncthreads();

    float* vrow = vals + (size_t)r * KSLOTS;
    unsigned short* crow = cols + (size_t)r * KSLOTS;
    for (int j = tid; j < KSLOTS; j += blockDim.x) { vrow[j] = slot_val[j]; crow[j] = slot_col[j]; }
}

// ---------------------------------------------------------------------------
// Coherent accesses at the coherence point (bypass L1+L2). Proven forms.
// ---------------------------------------------------------------------------
__device__ __forceinline__ f32x4 load_coherent_x4(const float* p) {
    f32x4 v;
    asm volatile("global_load_dwordx4 %0, %1, off sc0 sc1\n\t"
                 "s_waitcnt vmcnt(0)"
                 : "=v"(v) : "v"(p) : "memory");
    return v;
}

__device__ __forceinline__ void load_coherent_x4_pair(const float* p0, const float* p1,
                                                      f32x4* v0, f32x4* v1) {
    f32x4 a, b;
    asm volatile("global_load_dwordx4 %0, %2, off sc0 sc1\n\t"
                 "global_load_dwordx4 %1, %3, off sc0 sc1\n\t"
                 "s_waitcnt vmcnt(0)"
                 : "=v"(a), "=v"(b) : "v"(p0), "v"(p1) : "memory");
    *v0 = a; *v1 = b;
}

__device__ __forceinline__ void store_coherent_x4(float* p, f32x4 v) {
    asm volatile("global_store_dwordx4 %0, %1, off sc0 sc1"
                 :: "v"(p), "v"(v) : "memory");
}

__device__ __forceinline__ bool granule_not_ready(f32x4 hv) {
    return (__float_as_uint(hv.x) == SENTINEL_BITS) |
           (__float_as_uint(hv.y) == SENTINEL_BITS) |
           (__float_as_uint(hv.z) == SENTINEL_BITS) |
           (__float_as_uint(hv.w) == SENTINEL_BITS);
}

// 16B granule of 8 fp16 values: not ready iff ANY u16 == H16_SENT.
__device__ __forceinline__ bool h16_not_ready(f32x4 hv) {
    unsigned int w0 = __float_as_uint(hv.x), w1 = __float_as_uint(hv.y);
    unsigned int w2 = __float_as_uint(hv.z), w3 = __float_as_uint(hv.w);
    return ((w0 & 0xFFFFu) == H16_SENT) | ((w0 >> 16) == H16_SENT) |
           ((w1 & 0xFFFFu) == H16_SENT) | ((w1 >> 16) == H16_SENT) |
           ((w2 & 0xFFFFu) == H16_SENT) | ((w2 >> 16) == H16_SENT) |
           ((w3 & 0xFFFFu) == H16_SENT) | ((w3 >> 16) == H16_SENT);
}

// Branch-free tanh (validated R6-first-launch + R9: absmax 3.9e-3 unchanged).
__device__ __forceinline__ float fast_tanh(float v) {
    float ax = __builtin_fabsf(v);
    float e  = __builtin_amdgcn_exp2f(ax * 2.88539008177793f);  // 2*log2(e)
    float r  = 1.0f - 2.0f * __builtin_amdgcn_rcpf(e + 1.0f);
    return __builtin_copysignf(r, v);
}

// ---------------------------------------------------------------------------
// R19: 64-lane sum via the canonical GCN DPP ladder (pure VALU, off the LDS
// pipe). Lane 63 holds the total.
// ---------------------------------------------------------------------------
__device__ __forceinline__ float dpp_reduce_add(float v) {
    int t;
    t = __builtin_amdgcn_update_dpp(0, __float_as_int(v), 0x111, 0xf, 0xf, true); // shr:1
    v += __int_as_float(t);
    t = __builtin_amdgcn_update_dpp(0, __float_as_int(v), 0x112, 0xf, 0xf, true); // shr:2
    v += __int_as_float(t);
    t = __builtin_amdgcn_update_dpp(0, __float_as_int(v), 0x114, 0xf, 0xf, true); // shr:4
    v += __int_as_float(t);
    t = __builtin_amdgcn_update_dpp(0, __float_as_int(v), 0x118, 0xf, 0xf, true); // shr:8
    v += __int_as_float(t);
    t = __builtin_amdgcn_update_dpp(0, __float_as_int(v), 0x142, 0xa, 0xf, true); // bcast15
    v += __int_as_float(t);
    t = __builtin_amdgcn_update_dpp(0, __float_as_int(v), 0x143, 0xc, 0xf, true); // bcast31
    v += __int_as_float(t);
    return v;   // lane 63 = sum over all 64 lanes
}

// ---------------------------------------------------------------------------
// Kernel 2: persistent step kernel. R25 == R24 byte-identical (fp16 relay
// poll 2MB/round, detect==load, per-step staging, pi-layout staging writes
// at the 8-way floor, plain cached f32 out stores). The only change this
// round is build_ell's balancing key (see perm_bank).
// ---------------------------------------------------------------------------
__global__ void __launch_bounds__(NTHREADS, 1) esn_steps(
    const float* __restrict__ x,
    const float* __restrict__ W_in,
    const float* __restrict__ vals,
    const unsigned short* __restrict__ cols,
    float* __restrict__ out,
    char* __restrict__ h16,
    int use_h16) {

    __shared__ float h_lds[N];       // full previous state, 16 KB (pi layout)
    __shared__ __align__(16) float hout[ROWS_PER_BLOCK];  // block's 16 new rows

    const int tid  = threadIdx.x;
    const int lane = tid & 63;
    const int wave = tid >> 6;
    const int blockBase = blockIdx.x * ROWS_PER_BLOCK;
    const int base = blockBase + wave * ROWS_PER_WAVE;  // 2 rows/wave

    // Per-row W_in slices.
    float w0[ROWS_PER_WAVE], w1[ROWS_PER_WAVE];
    #pragma unroll
    for (int j = 0; j < ROWS_PER_WAVE; ++j) {
        w0[j] = W_in[(base + j) * IN_DIM + lane];
        w1[j] = W_in[(base + j) * IN_DIM + 64 + lane];
    }

    // Hoist the 2-row ELL slice into registers (18 vals + 18 byte offsets).
    // cols already hold pi(c): rc = pi(c)*4 = byte offset in the pi layout.
    float rv[ROWS_PER_WAVE][CHUNKS];
    int   rc[ROWS_PER_WAVE][CHUNKS];
    #pragma unroll
    for (int j = 0; j < ROWS_PER_WAVE; ++j) {
        const float* vp = vals + (size_t)(base + j) * KSLOTS;
        const unsigned short* cp = cols + (size_t)(base + j) * KSLOTS;
        #pragma unroll
        for (int i = 0; i < CHUNKS; ++i) {
            rv[j][i] = vp[(i << 6) + lane];
            rc[j][i] = ((int)cp[(i << 6) + lane]) << 2;
        }
    }

    const int i4 = tid << 2;
    const int gLo = (wave << 7) + lane;        // pi granule of h[8tid..8tid+4)
    const int gHi = gLo + 64;                  // pi granule of h[8tid+4..8tid+8)

    for (int t = 0; t < T_STEPS; ++t) {
        // ---- x_t via cached global loads (L1 broadcast) ----
        const float xa = x[t * IN_DIM + lane];
        const float xb = x[t * IN_DIM + 64 + lane];

        // ---- stage h_{t-1} ----
        if (t > 0) {
            if (use_h16) {
                // One 16B fp16 granule = 8 h values; proven paced ladder.
                const float* addr = (const float*)(h16 +
                    (size_t)(t - 1) * H16_BYTES_PER_STEP + (tid << 4));
                f32x4 hv;
                __builtin_amdgcn_s_sleep(8);
                hv = load_coherent_x4(addr);
                if (h16_not_ready(hv)) {
                    __builtin_amdgcn_s_sleep(1);
                    hv = load_coherent_x4(addr);
                    if (h16_not_ready(hv)) {
                        __builtin_amdgcn_s_sleep(2);
                        hv = load_coherent_x4(addr);
                        while (h16_not_ready(hv)) {
                            __builtin_amdgcn_s_sleep(4);
                            hv = load_coherent_x4(addr);
                        }
                    }
                }
                unsigned int u0 = __float_as_uint(hv.x), u1 = __float_as_uint(hv.y);
                unsigned int u2 = __float_as_uint(hv.z), u3 = __float_as_uint(hv.w);
                f32x4 lo, hi;
                lo.x = __half2float(__ushort_as_half((unsigned short)(u0 & 0xFFFFu)));
                lo.y = __half2float(__ushort_as_half((unsigned short)(u0 >> 16)));
                lo.z = __half2float(__ushort_as_half((unsigned short)(u1 & 0xFFFFu)));
                lo.w = __half2float(__ushort_as_half((unsigned short)(u1 >> 16)));
                hi.x = __half2float(__ushort_as_half((unsigned short)(u2 & 0xFFFFu)));
                hi.y = __half2float(__ushort_as_half((unsigned short)(u2 >> 16)));
                hi.z = __half2float(__ushort_as_half((unsigned short)(u3 & 0xFFFFu)));
                hi.w = __half2float(__ushort_as_half((unsigned short)(u3 >> 16)));
                ((f32x4*)h_lds)[gLo] = lo;     // bank group lane%8: 8-way floor
                ((f32x4*)h_lds)[gHi] = hi;
            } else {
                // Fallback: R22 paired f32 poll on out[t-1], pi-placed.
                f32x4 hv0, hv1;
                const float* a0 = out + (size_t)(t - 1) * N + i4;
                const float* a1 = a0 + (NTHREADS * 4);
                __builtin_amdgcn_s_sleep(8);
                load_coherent_x4_pair(a0, a1, &hv0, &hv1);
                if (granule_not_ready(hv0) | granule_not_ready(hv1)) {
                    __builtin_amdgcn_s_sleep(1);
                    load_coherent_x4_pair(a0, a1, &hv0, &hv1);
                    if (granule_not_ready(hv0) | granule_not_ready(hv1)) {
                        __builtin_amdgcn_s_sleep(2);
                        load_coherent_x4_pair(a0, a1, &hv0, &hv1);
                        while (granule_not_ready(hv0) | granule_not_ready(hv1)) {
                            __builtin_amdgcn_s_sleep(4);
                            load_coherent_x4_pair(a0, a1, &hv0, &hv1);
                        }
                    }
                }
                // f32 granule G holds cols [4G..4G+4): pi position
                const int G0 = tid, G1 = tid + NTHREADS;
                const int p0 = ((G0 >> 7) << 7) + ((G0 & 1) << 6) + ((G0 >> 1) & 63);
                const int p1 = ((G1 >> 7) << 7) + ((G1 & 1) << 6) + ((G1 >> 1) & 63);
                ((f32x4*)h_lds)[p0] = hv0;
                ((f32x4*)h_lds)[p1] = hv1;
            }
        } else {
            ((f32x4*)h_lds)[gLo] = (f32x4)(0.0f);
            ((f32x4*)h_lds)[gHi] = (f32x4)(0.0f);
        }
        __syncthreads();   // barrier 1: h_lds fully staged

        // ---- 2 row dots: input part + register-ELL sparse gather ----
        float acc[ROWS_PER_WAVE];
        #pragma unroll
        for (int j = 0; j < ROWS_PER_WAVE; ++j) acc[j] = w0[j] * xa + w1[j] * xb;

        #pragma unroll
        for (int j = 0; j < ROWS_PER_WAVE; ++j) {
            #pragma unroll
            for (int i = 0; i < CHUNKS; ++i) {
                acc[j] += rv[j][i] * *(const float*)((const char*)h_lds + rc[j][i]);
            }
        }

        // ---- DPP reduce (VALU pipe): lane 63 holds both sums ----
        acc[0] = dpp_reduce_add(acc[0]);
        acc[1] = dpp_reduce_add(acc[1]);

        if (lane == 63) {
            float hp0 = h_lds[perm_col(base + 0)];
            float hp1 = h_lds[perm_col(base + 1)];
            hout[wave * ROWS_PER_WAVE + 0] = 0.7f * hp0 + 0.3f * fast_tanh(acc[0]);
            hout[wave * ROWS_PER_WAVE + 1] = 0.7f * hp1 + 0.3f * fast_tanh(acc[1]);
        }
        __syncthreads();   // barrier 2: collect done + all h_lds reads done

        // ---- PUBLISH ----
        if (use_h16) {
            // fp16 relay line FIRST (the polled object): lanes 0-1, one 16B
            // coherent store each = the block's 32B line, single moment.
            if (tid < 2) {
                const float* hp = &hout[tid * 8];
                __half2 p0 = __floats2half2_rn(hp[0], hp[1]);
                __half2 p1 = __floats2half2_rn(hp[2], hp[3]);
                __half2 p2 = __floats2half2_rn(hp[4], hp[5]);
                __half2 p3 = __floats2half2_rn(hp[6], hp[7]);
                f32x4 pk;
                pk.x = __uint_as_float(*(unsigned int*)&p0);
                pk.y = __uint_as_float(*(unsigned int*)&p1);
                pk.z = __uint_as_float(*(unsigned int*)&p2);
                pk.w = __uint_as_float(*(unsigned int*)&p3);
                store_coherent_x4((float*)(h16 + (size_t)t * H16_BYTES_PER_STEP
                                           + blockIdx.x * 32 + (tid << 4)), pk);
            }
            // f32 out line: PLAIN cached stores (never polled; host sees it
            // via kernel-end writeback). hout is natural row order.
            if (tid < ROWS_PER_BLOCK / 4) {
                f32x4 hv4 = ((const f32x4*)hout)[tid];
                *(((f32x4*)(out + (size_t)t * N + blockBase)) + tid) = hv4;
            }
        } else {
            if (tid < ROWS_PER_BLOCK / 4) {
                f32x4 hv4 = ((const f32x4*)hout)[tid];
                store_coherent_x4(out + (size_t)t * N + blockBase + (tid << 2), hv4);
            }
        }
    }
}

// ---------------------------------------------------------------------------
// Workspace layout (bytes):
//   [0, +N*KSLOTS*4)       ELL vals (f32)            9.44 MB
//   [.., +N*KSLOTS*2)      ELL cols (u16)            4.72 MB
//   [.., +T_STEPS*N*2)     fp16 relay staging        16 MB  (guarded)
// Guard: if ws_size is short, use_h16=0 -> R22 behavior (pi-placed).
// ---------------------------------------------------------------------------
extern "C" void kernel_launch(void* const* d_in, const int* in_sizes, int n_in,
                              void* d_out, int out_size, void* d_ws, size_t ws_size,
                              hipStream_t stream) {
    const float* x    = (const float*)d_in[0];  // [2048,128]
    const float* W_in = (const float*)d_in[1];  // [4096,128]
    const float* W    = (const float*)d_in[2];  // [4096,4096]
    float* out = (float*)d_out;                 // [2048,4096]

    char* ws = (char*)d_ws;
    float* vals = (float*)ws;
    unsigned short* cols = (unsigned short*)(ws + (size_t)N * KSLOTS * 4);

    const size_t ell_bytes = (size_t)N * KSLOTS * 6;            // 14,155,776
    const size_t h16_bytes = (size_t)T_STEPS * H16_BYTES_PER_STEP;  // 16 MB
    int use_h16 = (ws_size >= ell_bytes + h16_bytes) ? 1 : 0;
    char* h16 = use_h16 ? (ws + ell_bytes) : nullptr;

    init_sentinel<<<(T_STEPS * N) / 1024, 1024, 0, stream>>>(
        out, (unsigned int*)h16);
    build_ell<<<N, 256, 0, stream>>>(W, vals, cols);

    void* args[] = {(void*)&x, (void*)&W_in, (void*)&vals, (void*)&cols,
                    (void*)&out, (void*)&h16, (void*)&use_h16};
    hipLaunchCooperativeKernel((void*)esn_steps, dim3(NBLOCKS), dim3(NTHREADS),
                               args, 0, stream);
}

// Round 17
// 3136.207 us; speedup vs baseline: 1.1067x; 1.0294x over previous
//
#include <hip/hip_runtime.h>

#define N 4096
#define IN_DIM 128
#define T_STEPS 2048
#define KSLOTS 576           // uniform padded ELL row width; max nnz ~490 (mean 409.6, sd 19.2)
#define CHUNKS (KSLOTS / 64) // 9, uniform for all rows (R21 packing REGRESSED: +11% conflicts)
#define NBLOCKS 256
#define NTHREADS 512
#define ROWS_PER_WAVE 2
#define ROWS_PER_BLOCK (ROWS_PER_WAVE * (NTHREADS / 64))   // 16
#define SENTINEL_BITS 0x7FC00001u   // qNaN; h is always finite -> producers never write this

typedef float f32x4 __attribute__((ext_vector_type(4)));

// ---------------------------------------------------------------------------
// R26 = exact revert to R22 (best proven: 3148 us), locking in the session's
// best kernel. The session's lever ledger, each closed by measurement:
//   - R11 full-line single-producer stores:        6515 -> 5089  (WIN)
//   - R13 paced poll ladder (sleep 8/1/2/4):       5089 -> 4599  (WIN)
//   - R19 DPP reduce + x off LDS:                  4599 -> 3267  (WIN)
//   - R22 256 blocks x 512 thr (halve LDS queue):  3267 -> 3148  (WIN)
//   - traffic halving via fp16 relay (R23-R25):    null at equal conflicts
//     -> broadcast is NOT bandwidth-limited; latency-bound serial chain
//   - poller-count reduction (R10/R12/R14/R16):    all regress (decouple tax)
//   - sub-MALL relay (R15/R17):                    unsound (XCD L2 non-coh.)
//   - pacing variants (R18 dual-slot, R20 early):  null / regress
//   - conflict shaping (R21 pack, R24/R25 perm):   floor is ~1.087e8
// Remaining chain @3690cy/step: gather ~1040 + detect ~1200 (entry 512 +
// MALL RT ~700) + store flight ~500 + reduce/barriers ~400. No counter
// shows a >5% structural lever within this architecture.
// ---------------------------------------------------------------------------

// ---------------------------------------------------------------------------
// Kernel 0: fill out with the sentinel, write-through (agent scope) so it is
// at the coherence point before any step-kernel poll. Defends against 0xAA
// poison and stale floats from a previous replay (both non-sentinel).
// ---------------------------------------------------------------------------
__global__ void init_sentinel(float* __restrict__ out) {
    const size_t i = (size_t)blockIdx.x * blockDim.x + threadIdx.x;
    __hip_atomic_store(&out[i], __uint_as_float(SENTINEL_BITS),
                       __ATOMIC_RELAXED, __HIP_MEMORY_SCOPE_AGENT);
}

// ---------------------------------------------------------------------------
// Kernel 1: dense W -> uniform padded ELL with bank-aware chunk assignment
// (each 64-slot chunk hits every LDS bank ~2x; 2-way is free on gfx950).
// Padding: val=0, col=0 (same-address broadcast, free). R19 version exactly —
// R21 taught that the zero-padding slots LOAD-BALANCE the banks (packing
// denser chunks raised conflicts 11%).
// ---------------------------------------------------------------------------
__global__ void build_ell(const float* __restrict__ W,
                          float* __restrict__ vals,
                          unsigned short* __restrict__ cols) {
    __shared__ float sval[KSLOTS];
    __shared__ unsigned short scol[KSLOTS];
    __shared__ float slot_val[KSLOTS];
    __shared__ unsigned short slot_col[KSLOTS];
    __shared__ int chunk_fill[CHUNKS];
    __shared__ int cnt;

    const int r = blockIdx.x;
    const int tid = threadIdx.x;
    if (tid == 0) cnt = 0;
    if (tid < CHUNKS) chunk_fill[tid] = 0;
    __syncthreads();

    const float* wrow = W + (size_t)r * N;
    for (int j = tid; j < N; j += blockDim.x) {
        float w = wrow[j];
        if (w != 0.0f) {
            int p = atomicAdd(&cnt, 1);
            if (p < KSLOTS) { sval[p] = w; scol[p] = (unsigned short)j; }
        }
    }
    __syncthreads();
    for (int j = tid; j < KSLOTS; j += blockDim.x) { slot_val[j] = 0.0f; slot_col[j] = 0; }
    __syncthreads();

    if (tid < 32) {  // one thread per bank spreads its entries across chunks
        int k = 0;
        const int n = (cnt < KSLOTS) ? cnt : KSLOTS;
        for (int p = 0; p < n; ++p) {
            int c = scol[p];
            if ((c & 31) == tid) {
                int ch0 = (k + tid) % CHUNKS;
                for (int probe = 0; probe < CHUNKS; ++probe) {
                    int cc = ch0 + probe; if (cc >= CHUNKS) cc -= CHUNKS;
                    int pos = atomicAdd(&chunk_fill[cc], 1);
                    if (pos < 64) {
                        slot_val[cc * 64 + pos] = sval[p];
                        slot_col[cc * 64 + pos] = (unsigned short)c;
                        break;
                    }
                }
                ++k;
            }
        }
    }
    __syncthreads();

    float* vrow = vals + (size_t)r * KSLOTS;
    unsigned short* crow = cols + (size_t)r * KSLOTS;
    for (int j = tid; j < KSLOTS; j += blockDim.x) { vrow[j] = slot_val[j]; crow[j] = slot_col[j]; }
}

// ---------------------------------------------------------------------------
// Coherent 16B accesses straight at the coherence point (bypass L1+L2).
// Single form is R4/R9-proven. The PAIRED form issues both loads back-to-back
// then waits ONCE — one RT per poll sample even though each thread stages two
// granules (512-thread blocks must cover 16KB of h).
// ---------------------------------------------------------------------------
__device__ __forceinline__ f32x4 load_coherent_x4(const float* p) {
    f32x4 v;
    asm volatile("global_load_dwordx4 %0, %1, off sc0 sc1\n\t"
                 "s_waitcnt vmcnt(0)"
                 : "=v"(v) : "v"(p) : "memory");
    return v;
}

__device__ __forceinline__ void load_coherent_x4_pair(const float* p0, const float* p1,
                                                      f32x4* v0, f32x4* v1) {
    f32x4 a, b;
    asm volatile("global_load_dwordx4 %0, %2, off sc0 sc1\n\t"
                 "global_load_dwordx4 %1, %3, off sc0 sc1\n\t"
                 "s_waitcnt vmcnt(0)"
                 : "=v"(a), "=v"(b) : "v"(p0), "v"(p1) : "memory");
    *v0 = a; *v1 = b;
}

__device__ __forceinline__ void store_coherent_x4(float* p, f32x4 v) {
    asm volatile("global_store_dwordx4 %0, %1, off sc0 sc1"
                 :: "v"(p), "v"(v) : "memory");
}

__device__ __forceinline__ bool granule_not_ready(f32x4 hv) {
    return (__float_as_uint(hv.x) == SENTINEL_BITS) |
           (__float_as_uint(hv.y) == SENTINEL_BITS) |
           (__float_as_uint(hv.z) == SENTINEL_BITS) |
           (__float_as_uint(hv.w) == SENTINEL_BITS);
}

// Branch-free tanh (validated R6-first-launch + R9: absmax 3.9e-3 unchanged).
__device__ __forceinline__ float fast_tanh(float v) {
    float ax = __builtin_fabsf(v);
    float e  = __builtin_amdgcn_exp2f(ax * 2.88539008177793f);  // 2*log2(e)
    float r  = 1.0f - 2.0f * __builtin_amdgcn_rcpf(e + 1.0f);
    return __builtin_copysignf(r, v);
}

// ---------------------------------------------------------------------------
// R19: full 64-lane sum via the canonical GCN DPP ladder (pure VALU, off the
// LDS pipe). Lane 63 holds the total.
// ---------------------------------------------------------------------------
__device__ __forceinline__ float dpp_reduce_add(float v) {
    int t;
    t = __builtin_amdgcn_update_dpp(0, __float_as_int(v), 0x111, 0xf, 0xf, true); // shr:1
    v += __int_as_float(t);
    t = __builtin_amdgcn_update_dpp(0, __float_as_int(v), 0x112, 0xf, 0xf, true); // shr:2
    v += __int_as_float(t);
    t = __builtin_amdgcn_update_dpp(0, __float_as_int(v), 0x114, 0xf, 0xf, true); // shr:4
    v += __int_as_float(t);
    t = __builtin_amdgcn_update_dpp(0, __float_as_int(v), 0x118, 0xf, 0xf, true); // shr:8
    v += __int_as_float(t);
    t = __builtin_amdgcn_update_dpp(0, __float_as_int(v), 0x142, 0xa, 0xf, true); // bcast15
    v += __int_as_float(t);
    t = __builtin_amdgcn_update_dpp(0, __float_as_int(v), 0x143, 0xc, 0xf, true); // bcast31
    v += __int_as_float(t);
    return v;   // lane 63 = sum over all 64 lanes
}

// ---------------------------------------------------------------------------
// Kernel 2: persistent step kernel (R22 exactly). 256 blocks x 512 threads:
// per-wave work identical to R19 (2 rows, 18-read gather, DPP reduce, x via
// cached global loads, qNaN data-as-flag, sleep(8)/1/2/steady-4 ladder), but
// 8 waves/CU on all 256 CUs halves the LDS gather serialization (the
// R19-validated bottleneck). Each thread stages TWO granules (paired load,
// one RT); block output = 16 rows = one 64B aligned single-wave burst.
// ---------------------------------------------------------------------------
__global__ void __launch_bounds__(NTHREADS, 1) esn_steps(
    const float* __restrict__ x,
    const float* __restrict__ W_in,
    const float* __restrict__ vals,
    const unsigned short* __restrict__ cols,
    float* __restrict__ out) {

    __shared__ float h_lds[N];       // full previous state, 16 KB
    __shared__ __align__(16) float hout[ROWS_PER_BLOCK];  // block's 16 new rows

    const int tid  = threadIdx.x;
    const int lane = tid & 63;
    const int wave = tid >> 6;
    const int blockBase = blockIdx.x * ROWS_PER_BLOCK;
    const int base = blockBase + wave * ROWS_PER_WAVE;  // 2 rows/wave

    // Per-row W_in slices.
    float w0[ROWS_PER_WAVE], w1[ROWS_PER_WAVE];
    #pragma unroll
    for (int j = 0; j < ROWS_PER_WAVE; ++j) {
        w0[j] = W_in[(base + j) * IN_DIM + lane];
        w1[j] = W_in[(base + j) * IN_DIM + 64 + lane];
    }

    // Hoist the 2-row ELL slice into registers (18 vals + 18 byte offsets).
    float rv[ROWS_PER_WAVE][CHUNKS];
    int   rc[ROWS_PER_WAVE][CHUNKS];
    #pragma unroll
    for (int j = 0; j < ROWS_PER_WAVE; ++j) {
        const float* vp = vals + (size_t)(base + j) * KSLOTS;
        const unsigned short* cp = cols + (size_t)(base + j) * KSLOTS;
        #pragma unroll
        for (int i = 0; i < CHUNKS; ++i) {
            rv[j][i] = vp[(i << 6) + lane];
            rc[j][i] = ((int)cp[(i << 6) + lane]) << 2;
        }
    }

    const int i4 = tid << 2;                 // first granule: floats [4t, 4t+4)
    // second granule: floats [4t + 2048, ...): covered by thread t as well

    for (int t = 0; t < T_STEPS; ++t) {
        // ---- x_t via cached global loads (L1 broadcast; issued before the
        //      poll so the latency hides under the ladder) ----
        const float xa = x[t * IN_DIM + lane];
        const float xb = x[t * IN_DIM + 64 + lane];

        // ---- stage h_{t-1}: paced paired-granule coherent poll ----
        f32x4 hv0, hv1;
        if (t > 0) {
            const float* a0 = out + (size_t)(t - 1) * N + i4;
            const float* a1 = a0 + (NTHREADS * 4);   // +2048 floats
            __builtin_amdgcn_s_sleep(8);           // skip guaranteed-miss round
            load_coherent_x4_pair(a0, a1, &hv0, &hv1);
            if (granule_not_ready(hv0) | granule_not_ready(hv1)) {
                __builtin_amdgcn_s_sleep(1);
                load_coherent_x4_pair(a0, a1, &hv0, &hv1);
                if (granule_not_ready(hv0) | granule_not_ready(hv1)) {
                    __builtin_amdgcn_s_sleep(2);
                    load_coherent_x4_pair(a0, a1, &hv0, &hv1);
                    while (granule_not_ready(hv0) | granule_not_ready(hv1)) {
                        __builtin_amdgcn_s_sleep(4);   // steady 256cy cap
                        load_coherent_x4_pair(a0, a1, &hv0, &hv1);
                    }
                }
            }
        } else {
            hv0 = (f32x4)(0.0f);
            hv1 = (f32x4)(0.0f);
        }
        ((f32x4*)h_lds)[tid] = hv0;
        ((f32x4*)h_lds)[tid + NTHREADS] = hv1;
        __syncthreads();   // barrier 1: h_lds fully staged

        // ---- 2 row dots: input part + register-ELL sparse gather ----
        float acc[ROWS_PER_WAVE];
        #pragma unroll
        for (int j = 0; j < ROWS_PER_WAVE; ++j) acc[j] = w0[j] * xa + w1[j] * xb;

        #pragma unroll
        for (int j = 0; j < ROWS_PER_WAVE; ++j) {
            #pragma unroll
            for (int i = 0; i < CHUNKS; ++i) {
                acc[j] += rv[j][i] * *(const float*)((const char*)h_lds + rc[j][i]);
            }
        }

        // ---- DPP reduce (VALU pipe, not LDS): lane 63 holds both sums ----
        acc[0] = dpp_reduce_add(acc[0]);
        acc[1] = dpp_reduce_add(acc[1]);

        // lane 63 finalizes both rows into the LDS collect buffer
        if (lane == 63) {
            float hp0 = h_lds[base + 0];
            float hp1 = h_lds[base + 1];
            hout[wave * ROWS_PER_WAVE + 0] = 0.7f * hp0 + 0.3f * fast_tanh(acc[0]);
            hout[wave * ROWS_PER_WAVE + 1] = 0.7f * hp1 + 0.3f * fast_tanh(acc[1]);
        }
        __syncthreads();   // barrier 2: collect done + all h_lds reads done

        // ---- wave 0 lanes 0..3 emit the block's 16 rows as one aligned 64B
        //      burst (sector-sized, single wave, single moment) ----
        if (tid < ROWS_PER_BLOCK / 4) {
            f32x4 hv4 = ((const f32x4*)hout)[tid];
            store_coherent_x4(out + (size_t)t * N + blockBase + (tid << 2), hv4);
        }
    }
}

// ---------------------------------------------------------------------------
// Workspace layout (bytes):
//   [0, +N*KSLOTS*4)       ELL vals (f32)   9.44 MB
//   [.., +N*KSLOTS*2)      ELL cols (u16)   4.72 MB
// ---------------------------------------------------------------------------
extern "C" void kernel_launch(void* const* d_in, const int* in_sizes, int n_in,
                              void* d_out, int out_size, void* d_ws, size_t ws_size,
                              hipStream_t stream) {
    const float* x    = (const float*)d_in[0];  // [2048,128]
    const float* W_in = (const float*)d_in[1];  // [4096,128]
    const float* W    = (const float*)d_in[2];  // [4096,4096]
    float* out = (float*)d_out;                 // [2048,4096]

    char* ws = (char*)d_ws;
    float* vals = (float*)ws;
    unsigned short* cols = (unsigned short*)(ws + (size_t)N * KSLOTS * 4);

    init_sentinel<<<(T_STEPS * N) / 1024, 1024, 0, stream>>>(out);
    build_ell<<<N, 256, 0, stream>>>(W, vals, cols);

    void* args[] = {(void*)&x, (void*)&W_in, (void*)&vals, (void*)&cols, (void*)&out};
    hipLaunchCooperativeKernel((void*)esn_steps, dim3(NBLOCKS), dim3(NTHREADS),
                               args, 0, stream);
}